// Round 5
// baseline (70.678 us; speedup 1.0000x reference)
//
#include <hip/hip_runtime.h>
#include <hip/hip_bf16.h>
#include <math.h>

#define MODES 32
#define BLOCK 256
#define TWO_PI 6.283185307179586f
#define INV_2PI 0.15915494309189535f
#define LROWW 36   // padded row stride in 4B words (72 bf16, 144B)

typedef __attribute__((ext_vector_type(8))) short bf16x8;
typedef __attribute__((ext_vector_type(4))) float f32x4;

__device__ __forceinline__ unsigned int pk_bf16(float a, float b) {
    __hip_bfloat162 h = __float22bfloat162_rn(float2{a, b});
    union { __hip_bfloat162 v; unsigned int u; } cv; cv.v = h;
    return cv.u;
}

// hi = bf16(a)|bf16(b) packed; lo = bf16 of residuals
__device__ __forceinline__ void split2(float a, float b, unsigned int& hi, unsigned int& lo) {
    hi = pk_bf16(a, b);
    const float ha = __uint_as_float((hi & 0xFFFFu) << 16);
    const float hb = __uint_as_float(hi & 0xFFFF0000u);
    lo = pk_bf16(a - ha, b - hb);
}

// ---------------- MFMA path (L == 4096 = 64 x 64) ----------------
// K[h, 64*i + j] = sum_k A[i,k] * B[k,j],  k = 2*mode (+1)
// A[i,2n]=2*Re(dC_n*W_n^i), A[i,2n+1]=-2*Im(dC_n*W_n^i),  W = dA^64
// B[2n,j]=Re(dA_n^j),       B[2n+1,j]=Im(dA_n^j)
// Each block: one h, one j-half (32 columns). Full A, half B in LDS.
__global__ __launch_bounds__(BLOCK, 5) void s4d_mfma(
    const float* __restrict__ log_dt,
    const float* __restrict__ C_real,
    const float* __restrict__ log_A_real,
    const float* __restrict__ A_imag,
    float* __restrict__ out)
{
    __shared__ __align__(16) unsigned int sAhi[64 * LROWW];
    __shared__ __align__(16) unsigned int sAlo[64 * LROWW];
    __shared__ __align__(16) unsigned int sBhi[32 * LROWW];  // BT[j_local][k]
    __shared__ __align__(16) unsigned int sBlo[32 * LROWW];
    __shared__ __align__(16) float s_cst[MODES][8]; // xr, rev, dcr2, dci2, dAr, dAi, Wr, Wi

    const int h  = blockIdx.x >> 1;
    const int jh = blockIdx.x & 1;       // j-half: columns [32*jh, 32*jh+32)
    const int t  = threadIdx.x;
    const int mode = t & 31;
    const int g    = t >> 5;             // 0..7

    // ---- per-mode discretization, once per block (32 lanes) ----
    if (t < MODES) {
        const int n = t;
        const float dt = __expf(log_dt[h]);
        const float ar = -__expf(log_A_real[h * MODES + n]);
        const float ai = A_imag[h * MODES + n];
        const float dtAr = ar * dt, dtAi = ai * dt;
        const float den_r = 1.0f - 0.5f * dtAr, den_i = -0.5f * dtAi;
        const float num_r = 1.0f + 0.5f * dtAr, num_i =  0.5f * dtAi;
        const float inv = 1.0f / (den_r * den_r + den_i * den_i);
        const float Br =  dt * den_r * inv;
        const float Bi = -dt * den_i * inv;
        const float Cr = C_real[(h * MODES + n) * 2 + 0];
        const float Ci = C_real[(h * MODES + n) * 2 + 1];
        const float dAr = (num_r * den_r + num_i * den_i) * inv;
        const float dAi = (num_i * den_r - num_r * den_i) * inv;
        const float xr  = 0.5f * __logf(dAr * dAr + dAi * dAi);
        const float rev = atan2f(dAi, dAr) * INV_2PI;
        // W = dA^64
        const float mag64 = __expf(64.0f * xr);
        float r64 = 64.0f * rev; r64 -= rintf(r64);
        float w_s, w_c; __sincosf(r64 * TWO_PI, &w_s, &w_c);
        s_cst[n][0] = xr;
        s_cst[n][1] = rev;
        s_cst[n][2] = 2.0f * (Cr * Br - Ci * Bi);
        s_cst[n][3] = 2.0f * (Cr * Bi + Ci * Br);
        s_cst[n][4] = dAr;
        s_cst[n][5] = dAi;
        s_cst[n][6] = mag64 * w_c;
        s_cst[n][7] = mag64 * w_s;
    }
    __syncthreads();

    const float4 c0 = *(const float4*)&s_cst[mode][0];
    const float4 c1 = *(const float4*)&s_cst[mode][4];
    const float xr = c0.x, rev = c0.y, dcr2 = c0.z, dci2 = c0.w;
    const float dAr = c1.x, dAi = c1.y, Wr = c1.z, Wi = c1.w;
    const float xr64 = 64.0f * xr;
    float r64 = 64.0f * rev; r64 -= rintf(r64);

    // ---- A gen: idx = 8g + b, b<8 (full 64 rows) ----
    {
        const float s = (float)(g * 8);
        float mags = __expf(xr64 * s);
        float ph2 = r64 * s; ph2 -= rintf(ph2);
        float sn2, cs2; __sincosf(ph2 * TWO_PI, &sn2, &cs2);
        const float wsr = mags * cs2, wsi = mags * sn2;
        float pr = dcr2 * wsr - dci2 * wsi;
        float pi = dcr2 * wsi + dci2 * wsr;
        int base = (g * 8) * LROWW + mode;
        #pragma unroll
        for (int b = 0; b < 8; ++b) {
            unsigned int hi, lo;
            split2(pr, -pi, hi, lo);
            sAhi[base] = hi; sAlo[base] = lo;
            const float npr = fmaf(pr, Wr, -(pi * Wi));
            const float npi = fmaf(pr, Wi,   pi * Wr);
            pr = npr; pi = npi;
            base += LROWW;
        }
    }
    // ---- B gen: j = 32*jh + 4g + b, b<4 (32 local rows) ----
    {
        const float j0 = (float)(jh * 32 + g * 4);
        float er = __expf(xr * j0);
        float ph = rev * j0; ph -= rintf(ph);
        float sn, cs; __sincosf(ph * TWO_PI, &sn, &cs);
        float br = er * cs, bi = er * sn;
        int base = (g * 4) * LROWW + mode;
        #pragma unroll
        for (int b = 0; b < 4; ++b) {
            unsigned int hi, lo;
            split2(br, bi, hi, lo);
            sBhi[base] = hi; sBlo[base] = lo;
            const float nbr = fmaf(br, dAr, -(bi * dAi));
            const float nbi = fmaf(br, dAi,   bi * dAr);
            br = nbr; bi = nbi;
            base += LROWW;
        }
    }
    __syncthreads();

    // -------- MFMA: wave wv computes rows [16wv, 16wv+16), 2 j-tiles --------
    const int wv   = t >> 6;
    const int lane = t & 63;
    const int c16  = lane & 15;
    const int quad = lane >> 4;

    const int arow = (wv * 16 + c16) * LROWW + quad * 4;
    const bf16x8 ah0 = *(const bf16x8*)&sAhi[arow];
    const bf16x8 ah1 = *(const bf16x8*)&sAhi[arow + 16];
    const bf16x8 al0 = *(const bf16x8*)&sAlo[arow];
    const bf16x8 al1 = *(const bf16x8*)&sAlo[arow + 16];

    float* op = out + ((size_t)h << 12) + (size_t)(wv * 16 + quad * 4) * 64
                    + jh * 32 + c16;

    #pragma unroll
    for (int nt = 0; nt < 2; ++nt) {
        const int brow = (nt * 16 + c16) * LROWW + quad * 4;
        const bf16x8 bh0 = *(const bf16x8*)&sBhi[brow];
        const bf16x8 bh1 = *(const bf16x8*)&sBhi[brow + 16];
        const bf16x8 bl0 = *(const bf16x8*)&sBlo[brow];
        const bf16x8 bl1 = *(const bf16x8*)&sBlo[brow + 16];

        f32x4 acc = {0.f, 0.f, 0.f, 0.f};
        acc = __builtin_amdgcn_mfma_f32_16x16x32_bf16(ah0, bh0, acc, 0, 0, 0);
        acc = __builtin_amdgcn_mfma_f32_16x16x32_bf16(ah1, bh1, acc, 0, 0, 0);
        acc = __builtin_amdgcn_mfma_f32_16x16x32_bf16(ah0, bl0, acc, 0, 0, 0);
        acc = __builtin_amdgcn_mfma_f32_16x16x32_bf16(ah1, bl1, acc, 0, 0, 0);
        acc = __builtin_amdgcn_mfma_f32_16x16x32_bf16(al0, bh0, acc, 0, 0, 0);
        acc = __builtin_amdgcn_mfma_f32_16x16x32_bf16(al1, bh1, acc, 0, 0, 0);

        #pragma unroll
        for (int r = 0; r < 4; ++r)
            op[(size_t)r * 64 + nt * 16] = acc[r];
    }
}

// ---------------- fallback: stride-256 real recurrence (any L % 256 == 0) ----------------
__global__ __launch_bounds__(BLOCK) void s4d_recur(
    const float* __restrict__ log_dt, const float* __restrict__ C_real,
    const float* __restrict__ log_A_real, const float* __restrict__ A_imag,
    float* __restrict__ out, int L)
{
    const int h = blockIdx.x, tid = threadIdx.x;
    const int P = L / BLOCK;
    __shared__ float4 s_c0[MODES], s_c1[MODES];
    if (tid < MODES) {
        const int n = tid;
        const float dt = __expf(log_dt[h]);
        const float ar = -__expf(log_A_real[h * MODES + n]);
        const float ai = A_imag[h * MODES + n];
        const float dtAr = ar * dt, dtAi = ai * dt;
        const float den_r = 1.0f - 0.5f * dtAr, den_i = -0.5f * dtAi;
        const float num_r = 1.0f + 0.5f * dtAr, num_i = 0.5f * dtAi;
        const float inv = 1.0f / (den_r * den_r + den_i * den_i);
        const float Brr = dt * den_r * inv, Bii = -dt * den_i * inv;
        const float Cr = C_real[(h * MODES + n) * 2 + 0];
        const float Ci = C_real[(h * MODES + n) * 2 + 1];
        const float dCr = Cr * Brr - Ci * Bii, dCi = Cr * Bii + Ci * Brr;
        const float dAr = (num_r * den_r + num_i * den_i) * inv;
        const float dAi = (num_i * den_r - num_r * den_i) * inv;
        const float xr = 0.5f * __logf(dAr * dAr + dAi * dAi);
        const float rev = atan2f(dAi, dAr) * INV_2PI;
        const float S = (float)BLOCK;
        const float mag = __expf(xr * S);
        float tt = rev * S; tt -= rintf(tt);
        float ws, wc; __sincosf(tt * TWO_PI, &ws, &wc);
        s_c0[n] = make_float4(xr, rev, 2.0f * dCr, 2.0f * dCi);
        s_c1[n] = make_float4(mag * wc, mag * ws, 2.0f * mag * wc, -(mag * mag));
    }
    __syncthreads();
    float m0[MODES], m1[MODES], aS[MODES], bS[MODES];
    float acc0 = 0.f, acc1 = 0.f;
    const float lf = (float)tid;
    #pragma unroll
    for (int n = 0; n < MODES; ++n) {
        const float4 c0 = s_c0[n]; const float4 c1 = s_c1[n];
        const float er = __expf(c0.x * lf);
        float tt = c0.y * lf; tt -= rintf(tt);
        float sn, cs; __sincosf(tt * TWO_PI, &sn, &cs);
        const float pr = er * cs, pi = er * sn;
        const float v0 = fmaf(c0.z, pr, -c0.w * pi);
        const float qr = fmaf(pr, c1.x, -pi * c1.y);
        const float qi = fmaf(pr, c1.y, pi * c1.x);
        const float v1 = fmaf(c0.z, qr, -c0.w * qi);
        m0[n] = v0; m1[n] = v1; acc0 += v0; acc1 += v1;
        aS[n] = c1.z; bS[n] = c1.w;
    }
    float* outp = out + (size_t)h * (size_t)L + tid;
    outp[0] = acc0;
    if (P > 1) outp[BLOCK] = acc1;
    int p = 2;
    for (; p + 1 < P; p += 2) {
        float accA = 0.f, accB = 0.f;
        #pragma unroll
        for (int n = 0; n < MODES; ++n) {
            const float mA = fmaf(aS[n], m1[n], bS[n] * m0[n]);
            const float mB = fmaf(aS[n], mA, bS[n] * m1[n]);
            accA += mA; accB += mB; m0[n] = mA; m1[n] = mB;
        }
        outp[(size_t)p * BLOCK] = accA;
        outp[(size_t)(p + 1) * BLOCK] = accB;
    }
    if (p < P) {
        float accA = 0.f;
        #pragma unroll
        for (int n = 0; n < MODES; ++n) {
            const float mA = fmaf(aS[n], m1[n], bS[n] * m0[n]);
            accA += mA; m0[n] = m1[n]; m1[n] = mA;
        }
        outp[(size_t)p * BLOCK] = accA;
    }
}

extern "C" void kernel_launch(void* const* d_in, const int* in_sizes, int n_in,
                              void* d_out, int out_size, void* d_ws, size_t ws_size,
                              hipStream_t stream) {
    const float* log_dt     = (const float*)d_in[0];
    const float* C_real     = (const float*)d_in[1];
    const float* log_A_real = (const float*)d_in[2];
    const float* A_imag     = (const float*)d_in[3];
    float* out = (float*)d_out;

    const int H = in_sizes[0];
    const int L = out_size / H;

    if (L == 4096) {
        s4d_mfma<<<H * 2, BLOCK, 0, stream>>>(log_dt, C_real, log_A_real, A_imag, out);
    } else {
        s4d_recur<<<H, BLOCK, 0, stream>>>(log_dt, C_real, log_A_real, A_imag, out, L);
    }
}